// Round 1
// baseline (446.004 us; speedup 1.0000x reference)
//
#include <hip/hip_runtime.h>

// SphereHashGridBackground: ray-sphere intersection + Instant-NGP hash grid encode.
// Reference constants (PER_LEVEL_SCALE == 2.0 exactly per reference comment):
//   level L: scale = 16*2^L - 1 in {15,31,63,127,255,511}, res = scale+1
//   levels 0..2 dense (res^3 <= 2^19), levels 3..5 hashed.
constexpr unsigned kHashmapSize = 1u << 19;
constexpr float kSphereR = 500.0f;

__global__ __launch_bounds__(256)
void sphere_hashgrid_kernel(const float* __restrict__ dirs,
                            const float* __restrict__ orig,
                            const float4* __restrict__ table4,
                            float* __restrict__ out,
                            int n_rays)
{
    int n = blockIdx.x * blockDim.x + threadIdx.x;
    if (n >= n_rays) return;

    // ---- load ray (stride-3 fp32 loads; 24 B/thread, small vs gather traffic)
    float dx = dirs[3 * n + 0], dy = dirs[3 * n + 1], dz = dirs[3 * n + 2];
    float ox = orig[3 * n + 0], oy = orig[3 * n + 1], oz = orig[3 * n + 2];

    // ---- ray-sphere intersection (a == 1, dirs normalized)
    float b = 2.0f * ((ox * dx + oy * dy) + oz * dz);
    float c = ((ox * ox + oy * oy) + oz * oz) - kSphereR * kSphereR;
    float disc = b * b - 4.0f * c;
    float t = (-b + sqrtf(fmaxf(disc, 0.0f))) * 0.5f;
    float px = ox + t * dx, py = oy + t * dy, pz = oz + t * dz;

    // coords in [0,1]
    float cx = fminf(fmaxf((px + kSphereR) / (2.0f * kSphereR), 0.0f), 1.0f);
    float cy = fminf(fmaxf((py + kSphereR) / (2.0f * kSphereR), 0.0f), 1.0f);
    float cz = fminf(fmaxf((pz + kSphereR) / (2.0f * kSphereR), 0.0f), 1.0f);

    constexpr float kScale[6] = {15.f, 31.f, 63.f, 127.f, 255.f, 511.f};
    constexpr unsigned kRes[6] = {16u, 32u, 64u, 128u, 256u, 512u};

    float* outp = out + (size_t)n * 24;

#pragma unroll
    for (int L = 0; L < 6; ++L) {
        const float sc = kScale[L];
        const unsigned res = kRes[L];
        const bool dense = (L < 3);

        float posx = cx * sc + 0.5f;
        float posy = cy * sc + 0.5f;
        float posz = cz * sc + 0.5f;
        float gx_f = floorf(posx), gy_f = floorf(posy), gz_f = floorf(posz);
        float fx = posx - gx_f, fy = posy - gy_f, fz = posz - gz_f;
        unsigned gx = (unsigned)gx_f, gy = (unsigned)gy_f, gz = (unsigned)gz_f;

        const float4* __restrict__ tl = table4 + (size_t)L * kHashmapSize;

        // compute all 8 indices first so the 8 gathers issue back-to-back (MLP)
        unsigned idx[8];
#pragma unroll
        for (int cr = 0; cr < 8; ++cr) {
            unsigned i = (unsigned)(cr >> 2);
            unsigned j = (unsigned)((cr >> 1) & 1);
            unsigned k = (unsigned)(cr & 1);
            unsigned x = gx + i, y = gy + j, z = gz + k;
            if (dense) {
                x = min(x, res - 1u);
                y = min(y, res - 1u);
                z = min(z, res - 1u);
                idx[cr] = x + y * res + z * res * res;
            } else {
                idx[cr] = (x * 1u ^ y * 2654435761u ^ z * 805459861u) & (kHashmapSize - 1u);
            }
        }

        float4 f[8];
#pragma unroll
        for (int cr = 0; cr < 8; ++cr) f[cr] = tl[idx[cr]];

        float wx[2] = {1.0f - fx, fx};
        float wy[2] = {1.0f - fy, fy};
        float wz[2] = {1.0f - fz, fz};

        float4 acc = make_float4(0.f, 0.f, 0.f, 0.f);
#pragma unroll
        for (int cr = 0; cr < 8; ++cr) {
            float w = (wx[(cr >> 2) & 1] * wy[(cr >> 1) & 1]) * wz[cr & 1];
            acc.x += f[cr].x * w;
            acc.y += f[cr].y * w;
            acc.z += f[cr].z * w;
            acc.w += f[cr].w * w;
        }

        *(float4*)(outp + L * 4) = acc;
    }
}

extern "C" void kernel_launch(void* const* d_in, const int* in_sizes, int n_in,
                              void* d_out, int out_size, void* d_ws, size_t ws_size,
                              hipStream_t stream) {
    const float* dirs = (const float*)d_in[0];       // view_dirs [N,3] f32
    const float* orig = (const float*)d_in[1];       // ray_origins [N,3] f32
    const float4* table4 = (const float4*)d_in[2];   // table [6, 2^19, 4] f32
    float* out = (float*)d_out;                      // [N, 24] f32

    int n_rays = in_sizes[0] / 3;
    const int block = 256;
    int grid = (n_rays + block - 1) / block;
    sphere_hashgrid_kernel<<<grid, block, 0, stream>>>(dirs, orig, table4, out, n_rays);
}

// Round 3
// 388.227 us; speedup vs baseline: 1.1488x; 1.1488x over previous
//
#include <hip/hip_runtime.h>

// SphereHashGridBackground: ray-sphere intersection + Instant-NGP hash grid encode.
// PER_LEVEL_SCALE == 2.0 exactly: level L scale = 16*2^L - 1 in {15,...,511},
// res = scale+1. Levels 0..2 dense (res^3 <= 2^19), levels 3..5 hashed.
constexpr unsigned kHashmapSize = 1u << 19;
constexpr float kSphereR = 500.0f;

// Native 4-float vector for nontemporal store (HIP_vector_type not accepted
// by __builtin_nontemporal_store).
typedef float v4f __attribute__((ext_vector_type(4)));

// LDS ray stride: 25 floats (24 data + 1 pad) -> ds_write_b128 lane banks are
// 25t mod 32 (25 coprime 32) = all-distinct across 32 lanes => 2-way for wave64 (free).
constexpr int kLdsStride = 25;

__global__ __launch_bounds__(256)
void sphere_hashgrid_kernel(const float* __restrict__ dirs,
                            const float* __restrict__ orig,
                            const float4* __restrict__ table4,
                            v4f* __restrict__ out4,
                            int n_rays)
{
    __shared__ float lds[256 * kLdsStride];

    const int t = threadIdx.x;
    const int n = blockIdx.x * 256 + t;
    const bool live = (n < n_rays);

    float cx = 0.f, cy = 0.f, cz = 0.f;
    if (live) {
        float dx = dirs[3 * n + 0], dy = dirs[3 * n + 1], dz = dirs[3 * n + 2];
        float ox = orig[3 * n + 0], oy = orig[3 * n + 1], oz = orig[3 * n + 2];

        // ray-sphere intersection (a == 1, dirs normalized)
        float b = 2.0f * ((ox * dx + oy * dy) + oz * dz);
        float c = ((ox * ox + oy * oy) + oz * oz) - kSphereR * kSphereR;
        float disc = b * b - 4.0f * c;
        float tt = (-b + sqrtf(fmaxf(disc, 0.0f))) * 0.5f;
        float px = ox + tt * dx, py = oy + tt * dy, pz = oz + tt * dz;

        cx = fminf(fmaxf((px + kSphereR) / (2.0f * kSphereR), 0.0f), 1.0f);
        cy = fminf(fmaxf((py + kSphereR) / (2.0f * kSphereR), 0.0f), 1.0f);
        cz = fminf(fmaxf((pz + kSphereR) / (2.0f * kSphereR), 0.0f), 1.0f);
    }

    constexpr float kScale[6] = {15.f, 31.f, 63.f, 127.f, 255.f, 511.f};
    constexpr unsigned kRes[6] = {16u, 32u, 64u, 128u, 256u, 512u};

#pragma unroll
    for (int L = 0; L < 6; ++L) {
        const float sc = kScale[L];
        const unsigned res = kRes[L];
        const bool dense = (L < 3);

        float posx = cx * sc + 0.5f;
        float posy = cy * sc + 0.5f;
        float posz = cz * sc + 0.5f;
        float gx_f = floorf(posx), gy_f = floorf(posy), gz_f = floorf(posz);
        float fx = posx - gx_f, fy = posy - gy_f, fz = posz - gz_f;
        unsigned gx = (unsigned)gx_f, gy = (unsigned)gy_f, gz = (unsigned)gz_f;

        const float4* __restrict__ tl = table4 + (size_t)L * kHashmapSize;

        unsigned idx[8];
#pragma unroll
        for (int cr = 0; cr < 8; ++cr) {
            unsigned i = (unsigned)(cr >> 2);
            unsigned j = (unsigned)((cr >> 1) & 1);
            unsigned k = (unsigned)(cr & 1);
            unsigned x = gx + i, y = gy + j, z = gz + k;
            if (dense) {
                x = min(x, res - 1u);
                y = min(y, res - 1u);
                z = min(z, res - 1u);
                idx[cr] = x + y * res + z * res * res;
            } else {
                idx[cr] = (x * 1u ^ y * 2654435761u ^ z * 805459861u) & (kHashmapSize - 1u);
            }
        }

        float4 f[8];
#pragma unroll
        for (int cr = 0; cr < 8; ++cr) f[cr] = live ? tl[idx[cr]] : make_float4(0,0,0,0);

        float wx[2] = {1.0f - fx, fx};
        float wy[2] = {1.0f - fy, fy};
        float wz[2] = {1.0f - fz, fz};

        float4 acc = make_float4(0.f, 0.f, 0.f, 0.f);
#pragma unroll
        for (int cr = 0; cr < 8; ++cr) {
            float w = (wx[(cr >> 2) & 1] * wy[(cr >> 1) & 1]) * wz[cr & 1];
            acc.x += f[cr].x * w;
            acc.y += f[cr].y * w;
            acc.z += f[cr].z * w;
            acc.w += f[cr].w * w;
        }

        *(float4*)(&lds[t * kLdsStride + L * 4]) = acc;
    }

    __syncthreads();

    // Coalesced, full-line output: block owns out4[block*1536 .. +1536).
    // flat float4 g = i*256 + t  ->  ray r = g/6, level e = g%6.
    const size_t base4 = (size_t)blockIdx.x * (256 * 6);
    const size_t total4 = (size_t)n_rays * 6;
#pragma unroll
    for (int i = 0; i < 6; ++i) {
        int g = i * 256 + t;
        int r = g / 6;
        int e = g - r * 6;
        v4f v = *(const v4f*)(&lds[r * kLdsStride + e * 4]);
        size_t go = base4 + (size_t)g;
        if (go < total4) __builtin_nontemporal_store(v, &out4[go]);
    }
}

extern "C" void kernel_launch(void* const* d_in, const int* in_sizes, int n_in,
                              void* d_out, int out_size, void* d_ws, size_t ws_size,
                              hipStream_t stream) {
    const float* dirs = (const float*)d_in[0];       // view_dirs [N,3] f32
    const float* orig = (const float*)d_in[1];       // ray_origins [N,3] f32
    const float4* table4 = (const float4*)d_in[2];   // table [6, 2^19, 4] f32
    v4f* out4 = (v4f*)d_out;                         // [N, 24] f32 as float4

    int n_rays = in_sizes[0] / 3;
    const int block = 256;
    int grid = (n_rays + block - 1) / block;
    sphere_hashgrid_kernel<<<grid, block, 0, stream>>>(dirs, orig, table4, out4, n_rays);
}